// Round 2
// baseline (406.998 us; speedup 1.0000x reference)
//
#include <hip/hip_runtime.h>
#include <hip/hip_bf16.h>

#define N_I 500000
#define N_H 200000
#define E1  2000000
#define E2  2000000

// Per-node precompute: g[n, 0:8] = x[n]^T @ W_edge  (W is [F,8] row-major fp32)
//                      g[n, 8]   = dot(x[n], b_edge)
// Stored with stride 12 floats (48 B) so float4 loads stay 16B-aligned.
// When ROOT: also out[n] = dot(x[n], Wr1+Wr2) + rb1 + rb2  (fp32 accumulator init
// for the aggregation — edge kernel atomicAdds on top).
template<int F, bool ROOT>
__global__ __launch_bounds__(256) void precompute_g(
    const float* __restrict__ x, const float* __restrict__ W, const float* __restrict__ b,
    float* __restrict__ g, int n,
    const float* __restrict__ rW1, const float* __restrict__ rW2,
    const float* __restrict__ rb1, const float* __restrict__ rb2,
    float* __restrict__ out)
{
    __shared__ float Wf[F * 8];
    __shared__ float bv[F];
    __shared__ float wr[F];

    for (int i = threadIdx.x; i < F * 8; i += 256) Wf[i] = W[i];
    if (threadIdx.x < F) {
        bv[threadIdx.x] = b[threadIdx.x];
        if (ROOT) wr[threadIdx.x] = rW1[threadIdx.x] + rW2[threadIdx.x];
    }
    __syncthreads();

    int nid = blockIdx.x * 256 + threadIdx.x;
    if (nid >= n) return;

    float xv[F];
    const float4* xp = (const float4*)(x + (size_t)nid * F);
    #pragma unroll
    for (int q = 0; q < F / 4; q++) {
        float4 v = xp[q];
        xv[q*4+0] = v.x; xv[q*4+1] = v.y; xv[q*4+2] = v.z; xv[q*4+3] = v.w;
    }

    float acc[9];
    #pragma unroll
    for (int k = 0; k < 9; k++) acc[k] = 0.f;

    #pragma unroll
    for (int j = 0; j < F; j++) {
        float4 w0 = *(const float4*)(Wf + j * 8);
        float4 w1 = *(const float4*)(Wf + j * 8 + 4);
        float xj = xv[j];
        acc[0] = fmaf(xj, w0.x, acc[0]);
        acc[1] = fmaf(xj, w0.y, acc[1]);
        acc[2] = fmaf(xj, w0.z, acc[2]);
        acc[3] = fmaf(xj, w0.w, acc[3]);
        acc[4] = fmaf(xj, w1.x, acc[4]);
        acc[5] = fmaf(xj, w1.y, acc[5]);
        acc[6] = fmaf(xj, w1.z, acc[6]);
        acc[7] = fmaf(xj, w1.w, acc[7]);
        acc[8] = fmaf(xj, bv[j], acc[8]);
    }

    float4* gp = (float4*)(g + (size_t)nid * 12);
    gp[0] = make_float4(acc[0], acc[1], acc[2], acc[3]);
    gp[1] = make_float4(acc[4], acc[5], acc[6], acc[7]);
    gp[2] = make_float4(acc[8], 0.f, 0.f, 0.f);

    if (ROOT) {
        float r = rb1[0] + rb2[0];
        #pragma unroll
        for (int j = 0; j < F; j++) r = fmaf(xv[j], wr[j], r);
        out[nid] = r;
    }
}

// One thread per edge across both relations. Grid covers E1+E2 exactly.
__global__ __launch_bounds__(256) void edge_kernel(
    const int* __restrict__ src1, const int* __restrict__ dst1,
    const float* __restrict__ ea1, const float* __restrict__ g1,
    const int* __restrict__ src2, const int* __restrict__ dst2,
    const float* __restrict__ ea2, const float* __restrict__ g2,
    float* __restrict__ out)
{
    int t = blockIdx.x * 256 + threadIdx.x;
    if (t >= E1 + E2) return;
    const int* srcp; const int* dstp; const float* eap; const float* gp;
    int e;
    if (t < E1) { e = t;      srcp = src1; dstp = dst1; eap = ea1; gp = g1; }
    else        { e = t - E1; srcp = src2; dstp = dst2; eap = ea2; gp = g2; }

    int s = srcp[e];
    int d = dstp[e];
    const float4* ap = (const float4*)(eap + (size_t)e * 8);
    float4 a0 = ap[0];
    float4 a1 = ap[1];
    const float4* gr = (const float4*)(gp + (size_t)s * 12);
    float4 ga = gr[0];
    float4 gb = gr[1];
    float4 gc = gr[2];

    float msg = gc.x;
    msg = fmaf(a0.x, ga.x, msg);
    msg = fmaf(a0.y, ga.y, msg);
    msg = fmaf(a0.z, ga.z, msg);
    msg = fmaf(a0.w, ga.w, msg);
    msg = fmaf(a1.x, gb.x, msg);
    msg = fmaf(a1.y, gb.y, msg);
    msg = fmaf(a1.z, gb.z, msg);
    msg = fmaf(a1.w, gb.w, msg);

    atomicAdd(out + d, msg);
}

extern "C" void kernel_launch(void* const* d_in, const int* in_sizes, int n_in,
                              void* d_out, int out_size, void* d_ws, size_t ws_size,
                              hipStream_t stream) {
    const float* x_i  = (const float*)d_in[0];
    const float* x_h  = (const float*)d_in[1];
    const float* ea_h = (const float*)d_in[2];
    const float* ea_i = (const float*)d_in[3];
    const float* We_h = (const float*)d_in[4];
    const float* be_h = (const float*)d_in[5];
    const float* We_i = (const float*)d_in[6];
    const float* be_i = (const float*)d_in[7];
    const float* Wr_h = (const float*)d_in[8];
    const float* br_h = (const float*)d_in[9];
    const float* Wr_i = (const float*)d_in[10];
    const float* br_i = (const float*)d_in[11];
    const int* src_h = (const int*)d_in[12];
    const int* dst_h = (const int*)d_in[13];
    const int* src_i = (const int*)d_in[14];
    const int* dst_i = (const int*)d_in[15];

    float* out = (float*)d_out;          // [N_I] fp32

    char* ws = (char*)d_ws;
    float* g_i = (float*)ws;             // 500000 * 12 floats = 24,000,000 B
    float* g_h = (float*)(ws + 24000000);// 200000 * 12 floats =  9,600,000 B
    // total ws use: 33.6 MB

    // Root transform initializes out; edge kernel accumulates on top (same stream).
    precompute_g<16, false><<<(N_H + 255) / 256, 256, 0, stream>>>(
        x_h, We_h, be_h, g_h, N_H, nullptr, nullptr, nullptr, nullptr, nullptr);
    precompute_g<32, true><<<(N_I + 255) / 256, 256, 0, stream>>>(
        x_i, We_i, be_i, g_i, N_I, Wr_h, Wr_i, br_h, br_i, out);
    edge_kernel<<<(E1 + E2 + 255) / 256, 256, 0, stream>>>(
        src_h, dst_h, ea_h, g_h, src_i, dst_i, ea_i, g_i, out);
}

// Round 3
// 384.897 us; speedup vs baseline: 1.0574x; 1.0574x over previous
//
#include <hip/hip_runtime.h>

#define N_I 500000
#define N_H 200000
#define E1  2000000
#define E2  2000000
#define TOTAL_E (E1 + E2)

#define NB 512                     // allocated buckets (dst >> 10); 489 used
#define CHUNK 8192                 // edges per workgroup in bucket pipeline
#define NWG ((TOTAL_E + CHUNK - 1) / CHUNK)        // = 489
#define NB_RED ((N_I + 1023) / 1024)               // = 489 reduce blocks

static_assert(NWG <= 512, "scan assumes <=512 workgroups");

// ---------------------------------------------------------------------------
// Per-node precompute: g[n, 0:8] = x[n]^T @ W_edge, g[n,8] = dot(x[n], b_edge)
// stride 12 floats. ROOT: out[n] = dot(x[n], Wr1+Wr2) + rb1 + rb2.
// ---------------------------------------------------------------------------
template<int F, bool ROOT>
__global__ __launch_bounds__(256) void precompute_g(
    const float* __restrict__ x, const float* __restrict__ W, const float* __restrict__ b,
    float* __restrict__ g, int n,
    const float* __restrict__ rW1, const float* __restrict__ rW2,
    const float* __restrict__ rb1, const float* __restrict__ rb2,
    float* __restrict__ out)
{
    __shared__ float Wf[F * 8];
    __shared__ float bv[F];
    __shared__ float wr[F];

    for (int i = threadIdx.x; i < F * 8; i += 256) Wf[i] = W[i];
    if (threadIdx.x < F) {
        bv[threadIdx.x] = b[threadIdx.x];
        if (ROOT) wr[threadIdx.x] = rW1[threadIdx.x] + rW2[threadIdx.x];
    }
    __syncthreads();

    int nid = blockIdx.x * 256 + threadIdx.x;
    if (nid >= n) return;

    float xv[F];
    const float4* xp = (const float4*)(x + (size_t)nid * F);
    #pragma unroll
    for (int q = 0; q < F / 4; q++) {
        float4 v = xp[q];
        xv[q*4+0] = v.x; xv[q*4+1] = v.y; xv[q*4+2] = v.z; xv[q*4+3] = v.w;
    }

    float acc[9];
    #pragma unroll
    for (int k = 0; k < 9; k++) acc[k] = 0.f;

    #pragma unroll
    for (int j = 0; j < F; j++) {
        float4 w0 = *(const float4*)(Wf + j * 8);
        float4 w1 = *(const float4*)(Wf + j * 8 + 4);
        float xj = xv[j];
        acc[0] = fmaf(xj, w0.x, acc[0]);
        acc[1] = fmaf(xj, w0.y, acc[1]);
        acc[2] = fmaf(xj, w0.z, acc[2]);
        acc[3] = fmaf(xj, w0.w, acc[3]);
        acc[4] = fmaf(xj, w1.x, acc[4]);
        acc[5] = fmaf(xj, w1.y, acc[5]);
        acc[6] = fmaf(xj, w1.z, acc[6]);
        acc[7] = fmaf(xj, w1.w, acc[7]);
        acc[8] = fmaf(xj, bv[j], acc[8]);
    }

    float4* gp = (float4*)(g + (size_t)nid * 12);
    gp[0] = make_float4(acc[0], acc[1], acc[2], acc[3]);
    gp[1] = make_float4(acc[4], acc[5], acc[6], acc[7]);
    gp[2] = make_float4(acc[8], 0.f, 0.f, 0.f);

    if (ROOT) {
        float r = rb1[0] + rb2[0];
        #pragma unroll
        for (int j = 0; j < F; j++) r = fmaf(xv[j], wr[j], r);
        out[nid] = r;
    }
}

// ---------------------------------------------------------------------------
// Shared per-edge message computation (both relations, unified index t).
// ---------------------------------------------------------------------------
__device__ __forceinline__ void edge_msg(
    int t,
    const int* __restrict__ src1, const int* __restrict__ dst1,
    const float* __restrict__ ea1, const float* __restrict__ g1,
    const int* __restrict__ src2, const int* __restrict__ dst2,
    const float* __restrict__ ea2, const float* __restrict__ g2,
    int& d_out, float& m_out)
{
    const int* srcp; const int* dstp; const float* eap; const float* gp;
    int e;
    if (t < E1) { e = t;      srcp = src1; dstp = dst1; eap = ea1; gp = g1; }
    else        { e = t - E1; srcp = src2; dstp = dst2; eap = ea2; gp = g2; }

    int s = srcp[e];
    d_out = dstp[e];
    const float4* ap = (const float4*)(eap + (size_t)e * 8);
    float4 a0 = ap[0];
    float4 a1 = ap[1];
    const float4* gr = (const float4*)(gp + (size_t)s * 12);
    float4 ga = gr[0];
    float4 gb = gr[1];
    float4 gc = gr[2];

    float msg = gc.x;
    msg = fmaf(a0.x, ga.x, msg);
    msg = fmaf(a0.y, ga.y, msg);
    msg = fmaf(a0.z, ga.z, msg);
    msg = fmaf(a0.w, ga.w, msg);
    msg = fmaf(a1.x, gb.x, msg);
    msg = fmaf(a1.y, gb.y, msg);
    msg = fmaf(a1.z, gb.z, msg);
    msg = fmaf(a1.w, gb.w, msg);
    m_out = msg;
}

// ---------------------------------------------------------------------------
// Bucket pipeline kernel A: compute msgs (coalesced store) + per-wg histogram.
// ---------------------------------------------------------------------------
__global__ __launch_bounds__(256) void msg_hist_kernel(
    const int* __restrict__ src1, const int* __restrict__ dst1,
    const float* __restrict__ ea1, const float* __restrict__ g1,
    const int* __restrict__ src2, const int* __restrict__ dst2,
    const float* __restrict__ ea2, const float* __restrict__ g2,
    float* __restrict__ msg_out, int* __restrict__ H)
{
    __shared__ int hist[NB];
    for (int i = threadIdx.x; i < NB; i += 256) hist[i] = 0;
    __syncthreads();

    int base = blockIdx.x * CHUNK;
    #pragma unroll 2
    for (int it = 0; it < CHUNK / 256; ++it) {
        int t = base + it * 256 + threadIdx.x;
        if (t < TOTAL_E) {
            int d; float m;
            edge_msg(t, src1, dst1, ea1, g1, src2, dst2, ea2, g2, d, m);
            msg_out[t] = m;
            atomicAdd(&hist[d >> 10], 1);
        }
    }
    __syncthreads();
    for (int i = threadIdx.x; i < NB; i += 256) H[blockIdx.x * NB + i] = hist[i];
}

// Kernel B: for each bucket (column b), exclusive scan over workgroups, in place.
// total[b] = column sum. Grid = NB blocks x 512 threads.
__global__ __launch_bounds__(512) void scan_cols_kernel(int* __restrict__ H,
                                                        int* __restrict__ total)
{
    __shared__ int v[512];
    int b = blockIdx.x;
    int tid = threadIdx.x;
    int orig = (tid < NWG) ? H[tid * NB + b] : 0;
    v[tid] = orig;
    __syncthreads();
    for (int off = 1; off < 512; off <<= 1) {
        int t = (tid >= off) ? v[tid - off] : 0;
        __syncthreads();
        v[tid] += t;
        __syncthreads();
    }
    if (tid < NWG) H[tid * NB + b] = v[tid] - orig;   // exclusive offset within bucket
    if (tid == 511) total[b] = v[511];
}

// Kernel C: exclusive scan of bucket totals -> base. 1 block x 512 threads.
__global__ __launch_bounds__(512) void scan_base_kernel(const int* __restrict__ total,
                                                        int* __restrict__ base)
{
    __shared__ int v[512];
    int tid = threadIdx.x;
    int orig = total[tid];
    v[tid] = orig;
    __syncthreads();
    for (int off = 1; off < 512; off <<= 1) {
        int t = (tid >= off) ? v[tid - off] : 0;
        __syncthreads();
        v[tid] += t;
        __syncthreads();
    }
    base[tid] = v[tid] - orig;
}

// Kernel E: scatter (dst, msg) pairs into bucket-sorted order via LDS cursors.
__global__ __launch_bounds__(256) void scatter_kernel(
    const int* __restrict__ dst1, const int* __restrict__ dst2,
    const float* __restrict__ msg, const int* __restrict__ H,
    const int* __restrict__ base, uint2* __restrict__ pairs)
{
    __shared__ int cur[NB];
    for (int i = threadIdx.x; i < NB; i += 256)
        cur[i] = H[blockIdx.x * NB + i] + base[i];
    __syncthreads();

    int cbase = blockIdx.x * CHUNK;
    #pragma unroll 2
    for (int it = 0; it < CHUNK / 256; ++it) {
        int t = cbase + it * 256 + threadIdx.x;
        if (t < TOTAL_E) {
            int d = (t < E1) ? dst1[t] : dst2[t - E1];
            float m = msg[t];
            int pos = atomicAdd(&cur[d >> 10], 1);
            pairs[pos] = make_uint2((unsigned)d, __float_as_uint(m));
        }
    }
}

// Kernel F: per-bucket reduction in LDS, then one coalesced out += acc.
__global__ __launch_bounds__(256) void reduce_kernel(
    const uint2* __restrict__ pairs, const int* __restrict__ base,
    const int* __restrict__ total, float* __restrict__ out)
{
    __shared__ float acc[1024];
    for (int i = threadIdx.x; i < 1024; i += 256) acc[i] = 0.f;
    __syncthreads();

    int b = blockIdx.x;
    int start = base[b];
    int cnt = total[b];
    for (int i = threadIdx.x; i < cnt; i += 256) {
        uint2 p = pairs[start + i];
        atomicAdd(&acc[p.x & 1023], __uint_as_float(p.y));
    }
    __syncthreads();

    int nb = b << 10;
    for (int i = threadIdx.x; i < 1024; i += 256) {
        int n = nb + i;
        if (n < N_I) out[n] += acc[i];
    }
}

// ---------------------------------------------------------------------------
// Fallback: proven round-2 atomic edge kernel (used only if ws too small).
// ---------------------------------------------------------------------------
__global__ __launch_bounds__(256) void edge_kernel_atomic(
    const int* __restrict__ src1, const int* __restrict__ dst1,
    const float* __restrict__ ea1, const float* __restrict__ g1,
    const int* __restrict__ src2, const int* __restrict__ dst2,
    const float* __restrict__ ea2, const float* __restrict__ g2,
    float* __restrict__ out)
{
    int t = blockIdx.x * 256 + threadIdx.x;
    if (t >= TOTAL_E) return;
    int d; float m;
    edge_msg(t, src1, dst1, ea1, g1, src2, dst2, ea2, g2, d, m);
    atomicAdd(out + d, m);
}

extern "C" void kernel_launch(void* const* d_in, const int* in_sizes, int n_in,
                              void* d_out, int out_size, void* d_ws, size_t ws_size,
                              hipStream_t stream) {
    const float* x_i  = (const float*)d_in[0];
    const float* x_h  = (const float*)d_in[1];
    const float* ea_h = (const float*)d_in[2];
    const float* ea_i = (const float*)d_in[3];
    const float* We_h = (const float*)d_in[4];
    const float* be_h = (const float*)d_in[5];
    const float* We_i = (const float*)d_in[6];
    const float* be_i = (const float*)d_in[7];
    const float* Wr_h = (const float*)d_in[8];
    const float* br_h = (const float*)d_in[9];
    const float* Wr_i = (const float*)d_in[10];
    const float* br_i = (const float*)d_in[11];
    const int* src_h = (const int*)d_in[12];
    const int* dst_h = (const int*)d_in[13];
    const int* src_i = (const int*)d_in[14];
    const int* dst_i = (const int*)d_in[15];

    float* out = (float*)d_out;

    // workspace layout
    char* ws = (char*)d_ws;
    float* g_i = (float*)ws;                           // 24,000,000 B
    float* g_h = (float*)(ws + 24000000);              //  9,600,000 B
    float* msg = (float*)(ws + 33600000);              // 16,000,000 B
    int*   H   = (int*)  (ws + 49600000);              //  1,001,472 B (489*512*4)
    int*   tot = (int*)  (ws + 50603008);              //      2,048 B
    int*   bas = (int*)  (ws + 50605056);              //      2,048 B
    // pairs aliases the g region (g dead after msg_hist_kernel): 32,000,000 B
    uint2* pairs = (uint2*)ws;
    const size_t WS_NEEDED = 50607104;

    precompute_g<16, false><<<(N_H + 255) / 256, 256, 0, stream>>>(
        x_h, We_h, be_h, g_h, N_H, nullptr, nullptr, nullptr, nullptr, nullptr);
    precompute_g<32, true><<<(N_I + 255) / 256, 256, 0, stream>>>(
        x_i, We_i, be_i, g_i, N_I, Wr_h, Wr_i, br_h, br_i, out);

    if (ws_size >= WS_NEEDED) {
        msg_hist_kernel<<<NWG, 256, 0, stream>>>(
            src_h, dst_h, ea_h, g_h, src_i, dst_i, ea_i, g_i, msg, H);
        scan_cols_kernel<<<NB, 512, 0, stream>>>(H, tot);
        scan_base_kernel<<<1, 512, 0, stream>>>(tot, bas);
        scatter_kernel<<<NWG, 256, 0, stream>>>(
            dst_h, dst_i, msg, H, bas, pairs);
        reduce_kernel<<<NB_RED, 256, 0, stream>>>(pairs, bas, tot, out);
    } else {
        edge_kernel_atomic<<<(TOTAL_E + 255) / 256, 256, 0, stream>>>(
            src_h, dst_h, ea_h, g_h, src_i, dst_i, ea_i, g_i, out);
    }
}